// Round 5
// baseline (648.237 us; speedup 1.0000x reference)
//
#include <hip/hip_runtime.h>

typedef __bf16 bf16x8 __attribute__((ext_vector_type(8)));
typedef __bf16 bf16x4 __attribute__((ext_vector_type(4)));
typedef float  floatx4 __attribute__((ext_vector_type(4)));
typedef float  f32x2   __attribute__((ext_vector_type(2)));

#define GLOBAL_AS __attribute__((address_space(1)))
#define LOCAL_AS  __attribute__((address_space(3)))

static constexpr int HID = 1024;
static constexpr int BK  = 64;        // K per tile
static constexpr int KIT = HID / BK;  // 16 K-tiles

// ---------------------------------------------------------------------------
// W1/B1 register slab for one K-octet (8 cols): 24 f32, held as f32x2 for
// packed VOP3P math (v_pk_fma_f32 / v_pk_max_f32).
// ---------------------------------------------------------------------------
struct W1Set { f32x2 w0[4], w1[4], b[4]; };

__device__ __forceinline__ void loadW1(W1Set& w, const float* __restrict__ W1,
                                       const float* __restrict__ B1,
                                       int kt, int octA) {
    const float* wp = W1 + kt * BK + octA * 8;
    const float4 a0 = *(const float4*)(wp);
    const float4 a1 = *(const float4*)(wp + 4);
    const float4 b0 = *(const float4*)(wp + HID);
    const float4 b1 = *(const float4*)(wp + HID + 4);
    const float4 c0 = *(const float4*)(B1 + kt * BK + octA * 8);
    const float4 c1 = *(const float4*)(B1 + kt * BK + octA * 8 + 4);
    w.w0[0] = (f32x2){a0.x, a0.y}; w.w0[1] = (f32x2){a0.z, a0.w};
    w.w0[2] = (f32x2){a1.x, a1.y}; w.w0[3] = (f32x2){a1.z, a1.w};
    w.w1[0] = (f32x2){b0.x, b0.y}; w.w1[1] = (f32x2){b0.z, b0.w};
    w.w1[2] = (f32x2){b1.x, b1.y}; w.w1[3] = (f32x2){b1.z, b1.w};
    w.b[0]  = (f32x2){c0.x, c0.y}; w.b[1]  = (f32x2){c0.z, c0.w};
    w.b[2]  = (f32x2){c1.x, c1.y}; w.b[3]  = (f32x2){c1.z, c1.w};
}

__device__ __forceinline__ void h8p(bf16x8& d, float s0, float s1,
                                    const W1Set& w) {
    const f32x2 s0v = {s0, s0}, s1v = {s1, s1};
#pragma unroll
    for (int i = 0; i < 4; ++i) {
        f32x2 v = __builtin_elementwise_fma(s1v, w.w1[i],
                    __builtin_elementwise_fma(s0v, w.w0[i], w.b[i]));
        v = __builtin_elementwise_max(v, (f32x2){0.f, 0.f});
        d[2 * i]     = (__bf16)v.x;
        d[2 * i + 1] = (__bf16)v.y;
    }
}

// ---------------------------------------------------------------------------
// prep (r4-verified layouts):
//   [0,256)    zero OUT
//   [256,512)  W2 [K][N] fp32 -> W2T K-octet-major bf16:
//              W2T[(((slab*16+kt)*8+oct)*256+col)*8 + j]
//                = W2[kt*64+oct*8+j][slab*256+col]
//   [512,544)  W_heads -> WHT[(k>>3)*256 + r*8 + (k&7)], r=s*4+a (<20), else 0
// ---------------------------------------------------------------------------
__global__ __launch_bounds__(256)
void prep_all(const float* __restrict__ W2, const float* __restrict__ WH,
              __bf16* __restrict__ W2T, __bf16* __restrict__ WHT,
              float* __restrict__ OUT) {
    int b = blockIdx.x;
    if (b < 256) {
        ((float4*)OUT)[(size_t)b * 256 + threadIdx.x]
            = make_float4(0.f, 0.f, 0.f, 0.f);
        return;
    }
    b -= 256;
    if (b < 256) {
        __shared__ __align__(16) __bf16 tile[64][72];  // [col][k], 16B-aligned rows
        const int bx = b & 15;   // 64-col group
        const int by = b >> 4;   // 64-k group (= kt)
        const int a  = threadIdx.x & 63;
        const int bb = threadIdx.x >> 6;  // 0..3
#pragma unroll
        for (int r = 0; r < 16; ++r) {
            const int k = r * 4 + bb;
            tile[a][k] = (__bf16)W2[(size_t)(by * 64 + k) * HID + bx * 64 + a];
        }
        __syncthreads();
        const int slab = bx >> 2;
#pragma unroll
        for (int p = 0; p < 2; ++p) {
            const int idx = p * 256 + threadIdx.x;   // 0..511
            const int c   = idx & 63;
            const int oct = idx >> 6;                // 0..7
            const bf16x8 v = *(const bf16x8*)&tile[c][oct * 8];
            const int col = (bx & 3) * 64 + c;
            const size_t dst = ((size_t)(slab * KIT + by) * 8 + oct) * 256 + col;
            *(bf16x8*)(W2T + dst * 8) = v;
        }
    } else {
        const int r = b - 256;             // 0..31
        const int s = r >> 2, a = r & 3;
        for (int k = threadIdx.x; k < HID; k += 256) {
            const float v = (r < 20) ? WH[((size_t)s * HID + k) * 4 + a] : 0.f;
            WHT[(size_t)(k >> 3) * 256 + r * 8 + (k & 7)] = (__bf16)v;
        }
    }
}

// ---------------------------------------------------------------------------
// r4 structure (64x256 tile, 4 waves, 2-barrier K-loop, 40960 B LDS,
// ~3 blocks/CU) + two latency/VALU cuts:
//   (1) W1/B1 register slab pipelined ONE TILE AHEAD (kt consumes regs loaded
//       at kt-1; loads for kt+1 issue right after the B-gloads) -> h8 starts
//       immediately and its VALU covers B-staging latency instead of
//       following a ~300-cyc W1 vmcnt stall.
//   (2) h8 in packed f32x2 math (v_pk_fma_f32 / v_pk_max_f32): ~16 ops vs 28.
// K-loop unrolled x2 with two named W1Set regs (static indexing, no moves).
// ---------------------------------------------------------------------------
__global__ __launch_bounds__(256, 4)
void policy_main(const float* __restrict__ S,  const int* __restrict__ SK,
                 const float* __restrict__ W1, const float* __restrict__ B1,
                 const __bf16* __restrict__ W2T, const float* __restrict__ B2,
                 const __bf16* __restrict__ WHT, const float* __restrict__ BH,
                 float* __restrict__ OUT) {
    __shared__ __align__(16) char smem[40960];
    __bf16* At    = (__bf16*)smem;            // [8 oct][64 smp][8]  = 8 KiB
    __bf16* Bt    = (__bf16*)(smem + 8192);   // [8 oct][256 col][8] = 32 KiB
    __bf16* featL = (__bf16*)(smem + 8192);   // overlay [32 oct][64 smp][8]

    const int tid  = threadIdx.x;
    const int lane = tid & 63;
    const int wv   = tid >> 6;       // 0..3  (featcol strip of 64)
    const int l15  = lane & 15;
    const int quad = lane >> 4;
    const int slab = blockIdx.x >> 10;      // 0..3 (256-col slab)
    const int g    = blockIdx.x & 1023;     // sample group
    const size_t i0 = (size_t)g * 64;

    const int octA = wv * 2 + (lane >> 5);  // A-compute k-octet
    const int smpA = lane & 31;             // A-compute sample

    floatx4 acc[4][4] = {};   // [fn featcol-frag][fm sample-frag]

    // ---- prologue: this lane's 2 sample states + W1 slab for tile 0
    const float2 sv0 = *(const float2*)(S + (i0 + smpA) * 2);
    const float2 sv1 = *(const float2*)(S + (i0 + 32 + smpA) * 2);

    auto stageB = [&](int kt) {
#pragma unroll
        for (int L = 0; L < 8; ++L) {
            const __bf16* gp = W2T
                + (((size_t)(slab * KIT + kt) * 8 + L) * 256 + wv * 64 + lane) * 8;
            __builtin_amdgcn_global_load_lds((GLOBAL_AS void*)gp,
                (LOCAL_AS void*)(Bt + (L * 256 + wv * 64) * 8), 16, 0, 0);
        }
    };
    auto writeA = [&](const W1Set& w) {
        bf16x8 hv;
        h8p(hv, sv0.x, sv0.y, w);
        *(bf16x8*)(At + (octA * 64 + smpA) * 8) = hv;
        h8p(hv, sv1.x, sv1.y, w);
        *(bf16x8*)(At + (octA * 64 + 32 + smpA) * 8) = hv;
    };
    auto mfmaPhase = [&]() {
#pragma unroll
        for (int ks = 0; ks < 2; ++ks) {
            bf16x8 wf[4], hf[4];
#pragma unroll
            for (int f = 0; f < 4; ++f)
                wf[f] = *(const bf16x8*)(Bt
                         + (((ks * 4 + quad) * 256) + wv * 64 + f * 16 + l15) * 8);
#pragma unroll
            for (int f = 0; f < 4; ++f)
                hf[f] = *(const bf16x8*)(At
                         + (((ks * 4 + quad) * 64) + f * 16 + l15) * 8);
#pragma unroll
            for (int fn = 0; fn < 4; ++fn)
#pragma unroll
                for (int fm = 0; fm < 4; ++fm)
                    acc[fn][fm] = __builtin_amdgcn_mfma_f32_16x16x32_bf16(
                        wf[fn], hf[fm], acc[fn][fm], 0, 0, 0);
        }
    };

    W1Set wEven, wOdd;
    loadW1(wEven, W1, B1, 0, octA);

#pragma unroll 1
    for (int kt = 0; kt < KIT; kt += 2) {
        // ---- even tile: consume wEven, prefetch wOdd for kt+1
        __syncthreads();              // previous tile's frag readers done
        stageB(kt);
        loadW1(wOdd, W1, B1, kt + 1, octA);   // issue early; consumed next tile
        writeA(wEven);                // regs ready -> h8 covers B latency
        __syncthreads();              // drain staging + A writes
        mfmaPhase();

        // ---- odd tile: consume wOdd, prefetch wEven for kt+2
        __syncthreads();
        stageB(kt + 1);
        if (kt + 2 < KIT) loadW1(wEven, W1, B1, kt + 2, octA);
        writeA(wOdd);
        __syncthreads();
        mfmaPhase();
    }

    // ---- epilogue: relu(acc + b2) -> featL (K-octet-major overlay over Bt)
    __syncthreads();
#pragma unroll
    for (int fn = 0; fn < 4; ++fn) {
        const int fcb = wv * 64 + fn * 16 + quad * 4;   // featcol base
        const float4 b2v = *(const float4*)(B2 + slab * 256 + fcb);
        const int o = fcb >> 3, j = fcb & 7;
#pragma unroll
        for (int fm = 0; fm < 4; ++fm) {
            const int smp = fm * 16 + l15;
            const floatx4 v = acc[fn][fm];
            bf16x4 p;
            p[0] = (__bf16)fmaxf(v[0] + b2v.x, 0.f);
            p[1] = (__bf16)fmaxf(v[1] + b2v.y, 0.f);
            p[2] = (__bf16)fmaxf(v[2] + b2v.z, 0.f);
            p[3] = (__bf16)fmaxf(v[3] + b2v.w, 0.f);
            *(bf16x4*)(featL + (o * 64 + smp) * 8 + j) = p;
        }
    }
    __syncthreads();

    // ---- head MFMA: wave wv -> samples wv*16..+15; WHT direct (L2-hot)
    floatx4 hacc[2] = {};
#pragma unroll
    for (int ks2 = 0; ks2 < 8; ++ks2) {
        const bf16x8 fa = *(const bf16x8*)(featL
                             + ((ks2 * 4 + quad) * 64 + wv * 16 + l15) * 8);
#pragma unroll
        for (int t2 = 0; t2 < 2; ++t2) {
            const int r  = t2 * 16 + l15;
            const int og = slab * 32 + ks2 * 4 + quad;
            const bf16x8 wb = *(const bf16x8*)(WHT + (size_t)og * 256 + r * 8);
            hacc[t2] = __builtin_amdgcn_mfma_f32_16x16x32_bf16(
                fa, wb, hacc[t2], 0, 0, 0);
        }
    }

    // ---- atomic scatter: sample = quad*4+reg; emit selected skill's 4 actions
#pragma unroll
    for (int j = 0; j < 4; ++j) {
        const int smp = wv * 16 + quad * 4 + j;
        const int sk  = SK[i0 + smp];
#pragma unroll
        for (int t2 = 0; t2 < 2; ++t2) {
            const int hc = t2 * 16 + l15;
            const int d  = hc - sk * 4;
            if (d >= 0 && d < 4) {
                float v = hacc[t2][j];
                if (slab == 0) v += BH[hc];
                atomicAdd(&OUT[(i0 + smp) * 4 + d], v);
            }
        }
    }
}

extern "C" void kernel_launch(void* const* d_in, const int* in_sizes, int n_in,
                              void* d_out, int out_size, void* d_ws, size_t ws_size,
                              hipStream_t stream) {
    const float* S  = (const float*)d_in[0];
    const int*   SK = (const int*)d_in[1];
    const float* W1 = (const float*)d_in[2];
    const float* B1 = (const float*)d_in[3];
    const float* W2 = (const float*)d_in[4];
    const float* B2 = (const float*)d_in[5];
    const float* WH = (const float*)d_in[6];
    const float* BH = (const float*)d_in[7];

    char* ws = (char*)d_ws;
    __bf16* W2T = (__bf16*)ws;                          // 2 MiB
    __bf16* WHT = (__bf16*)(ws + 2 * 1024 * 1024);      // 64 KiB

    hipLaunchKernelGGL(prep_all, dim3(544), dim3(256), 0, stream,
                       W2, WH, W2T, WHT, (float*)d_out);
    // grid: 1024 sample-groups x 4 slabs; slab = blockIdx>>10 so co-resident
    // blocks share one W2T slab (L2-friendly)
    hipLaunchKernelGGL(policy_main, dim3(4096), dim3(256), 0, stream,
                       S, SK, W1, B1, W2T, B2, WHT, BH, (float*)d_out);
}

// Round 6
// 285.810 us; speedup vs baseline: 2.2681x; 2.2681x over previous
//
#include <hip/hip_runtime.h>

typedef __bf16 bf16x8 __attribute__((ext_vector_type(8)));
typedef __bf16 bf16x4 __attribute__((ext_vector_type(4)));
typedef float  floatx4 __attribute__((ext_vector_type(4)));

#define GLOBAL_AS __attribute__((address_space(1)))
#define LOCAL_AS  __attribute__((address_space(3)))

static constexpr int HID = 1024;
static constexpr int BK  = 64;        // K per tile
static constexpr int KIT = HID / BK;  // 16 K-tiles

__device__ __forceinline__ void h8(bf16x8& d, float s0, float s1,
                                   const float4& w0a, const float4& w0b,
                                   const float4& w1a, const float4& w1b,
                                   const float4& ba,  const float4& bb) {
    d[0] = (__bf16)fmaxf(fmaf(s1, w1a.x, fmaf(s0, w0a.x, ba.x)), 0.f);
    d[1] = (__bf16)fmaxf(fmaf(s1, w1a.y, fmaf(s0, w0a.y, ba.y)), 0.f);
    d[2] = (__bf16)fmaxf(fmaf(s1, w1a.z, fmaf(s0, w0a.z, ba.z)), 0.f);
    d[3] = (__bf16)fmaxf(fmaf(s1, w1a.w, fmaf(s0, w0a.w, ba.w)), 0.f);
    d[4] = (__bf16)fmaxf(fmaf(s1, w1b.x, fmaf(s0, w0b.x, bb.x)), 0.f);
    d[5] = (__bf16)fmaxf(fmaf(s1, w1b.y, fmaf(s0, w0b.y, bb.y)), 0.f);
    d[6] = (__bf16)fmaxf(fmaf(s1, w1b.z, fmaf(s0, w0b.z, bb.z)), 0.f);
    d[7] = (__bf16)fmaxf(fmaf(s1, w1b.w, fmaf(s0, w0b.w, bb.w)), 0.f);
}

// ---------------------------------------------------------------------------
// prep (r4-verified layouts, byte-identical):
//   [0,256)    zero OUT
//   [256,512)  W2 [K][N] fp32 -> W2T K-octet-major bf16:
//              W2T[(((slab*16+kt)*8+oct)*256+col)*8 + j]
//                = W2[kt*64+oct*8+j][slab*256+col]
//   [512,544)  W_heads -> WHT[(k>>3)*256 + r*8 + (k&7)], r=s*4+a (<20), else 0
// ---------------------------------------------------------------------------
__global__ __launch_bounds__(256)
void prep_all(const float* __restrict__ W2, const float* __restrict__ WH,
              __bf16* __restrict__ W2T, __bf16* __restrict__ WHT,
              float* __restrict__ OUT) {
    int b = blockIdx.x;
    if (b < 256) {
        ((float4*)OUT)[(size_t)b * 256 + threadIdx.x]
            = make_float4(0.f, 0.f, 0.f, 0.f);
        return;
    }
    b -= 256;
    if (b < 256) {
        __shared__ __align__(16) __bf16 tile[64][72];  // [col][k], 16B-aligned rows
        const int bx = b & 15;   // 64-col group
        const int by = b >> 4;   // 64-k group (= kt)
        const int a  = threadIdx.x & 63;
        const int bb = threadIdx.x >> 6;  // 0..3
#pragma unroll
        for (int r = 0; r < 16; ++r) {
            const int k = r * 4 + bb;
            tile[a][k] = (__bf16)W2[(size_t)(by * 64 + k) * HID + bx * 64 + a];
        }
        __syncthreads();
        const int slab = bx >> 2;
#pragma unroll
        for (int p = 0; p < 2; ++p) {
            const int idx = p * 256 + threadIdx.x;   // 0..511
            const int c   = idx & 63;
            const int oct = idx >> 6;                // 0..7
            const bf16x8 v = *(const bf16x8*)&tile[c][oct * 8];
            const int col = (bx & 3) * 64 + c;
            const size_t dst = ((size_t)(slab * KIT + by) * 8 + oct) * 256 + col;
            *(bf16x8*)(W2T + dst * 8) = v;
        }
    } else {
        const int r = b - 256;             // 0..31
        const int s = r >> 2, a = r & 3;
        for (int k = threadIdx.x; k < HID; k += 256) {
            const float v = (r < 20) ? WH[((size_t)s * HID + k) * 4 + a] : 0.f;
            WHT[(size_t)(k >> 3) * 256 + r * 8 + (k & 7)] = (__bf16)v;
        }
    }
}

// ---------------------------------------------------------------------------
// r4 structure (64x256 tile, 4 waves, 2-barrier K-loop, 40960 B LDS,
// ~3 blocks/CU) + W1/B1 register slab pipelined ONE TILE AHEAD, expressed as
// named float4 locals with a manually x2-unrolled kt-loop (NO structs, NO
// lambdas, nothing address-taken -- r5's W1Set/lambda version spilled to
// scratch: 2.27 GB of HBM spill traffic, 614 us; this is the scratch-proof
// form of the same schedule). h8 consumes regs loaded LAST tile, so its
// ~110-cyc VALU burst starts immediately after the B-gload issues and covers
// their latency; the W1 L2 round-trip is hidden across a whole tile.
// ---------------------------------------------------------------------------
__global__ __launch_bounds__(256, 3)
void policy_main(const float* __restrict__ S,  const int* __restrict__ SK,
                 const float* __restrict__ W1, const float* __restrict__ B1,
                 const __bf16* __restrict__ W2T, const float* __restrict__ B2,
                 const __bf16* __restrict__ WHT, const float* __restrict__ BH,
                 float* __restrict__ OUT) {
    __shared__ __align__(16) char smem[40960];
    __bf16* At    = (__bf16*)smem;            // [8 oct][64 smp][8]  = 8 KiB
    __bf16* Bt    = (__bf16*)(smem + 8192);   // [8 oct][256 col][8] = 32 KiB
    __bf16* featL = (__bf16*)(smem + 8192);   // overlay [32 oct][64 smp][8]

    const int tid  = threadIdx.x;
    const int lane = tid & 63;
    const int wv   = tid >> 6;       // 0..3  (featcol strip of 64)
    const int l15  = lane & 15;
    const int quad = lane >> 4;
    const int slab = blockIdx.x >> 10;      // 0..3 (256-col slab)
    const int g    = blockIdx.x & 1023;     // sample group
    const size_t i0 = (size_t)g * 64;

    const int octA = wv * 2 + (lane >> 5);  // A-compute k-octet
    const int smpA = lane & 31;             // A-compute sample

    floatx4 acc[4][4] = {};   // [fn featcol-frag][fm sample-frag]

    // ---- prologue: this lane's 2 sample states
    const float2 sv0 = *(const float2*)(S + (i0 + smpA) * 2);
    const float2 sv1 = *(const float2*)(S + (i0 + 32 + smpA) * 2);

    // ---- W1/B1 double-buffered register slabs (named, static — no scratch)
    const float* wbase = W1 + octA * 8;
    const float* bbase = B1 + octA * 8;
    float4 e_w0a = *(const float4*)(wbase);
    float4 e_w0b = *(const float4*)(wbase + 4);
    float4 e_w1a = *(const float4*)(wbase + HID);
    float4 e_w1b = *(const float4*)(wbase + HID + 4);
    float4 e_ba  = *(const float4*)(bbase);
    float4 e_bb  = *(const float4*)(bbase + 4);
    float4 o_w0a, o_w0b, o_w1a, o_w1b, o_ba, o_bb;

#pragma unroll 1
    for (int kt = 0; kt < KIT; kt += 2) {
        // ================= even tile kt: consume E set, load O for kt+1 ======
        __syncthreads();   // previous tile's frag readers done
#pragma unroll
        for (int L = 0; L < 8; ++L) {
            const __bf16* gp = W2T
                + (((size_t)(slab * KIT + kt) * 8 + L) * 256 + wv * 64 + lane) * 8;
            __builtin_amdgcn_global_load_lds((GLOBAL_AS void*)gp,
                (LOCAL_AS void*)(Bt + (L * 256 + wv * 64) * 8), 16, 0, 0);
        }
        o_w0a = *(const float4*)(wbase + (kt + 1) * BK);
        o_w0b = *(const float4*)(wbase + (kt + 1) * BK + 4);
        o_w1a = *(const float4*)(wbase + (kt + 1) * BK + HID);
        o_w1b = *(const float4*)(wbase + (kt + 1) * BK + HID + 4);
        o_ba  = *(const float4*)(bbase + (kt + 1) * BK);
        o_bb  = *(const float4*)(bbase + (kt + 1) * BK + 4);
        {
            bf16x8 hv;
            h8(hv, sv0.x, sv0.y, e_w0a, e_w0b, e_w1a, e_w1b, e_ba, e_bb);
            *(bf16x8*)(At + (octA * 64 + smpA) * 8) = hv;
            h8(hv, sv1.x, sv1.y, e_w0a, e_w0b, e_w1a, e_w1b, e_ba, e_bb);
            *(bf16x8*)(At + (octA * 64 + 32 + smpA) * 8) = hv;
        }
        __syncthreads();   // drain staging + A writes
#pragma unroll
        for (int ks = 0; ks < 2; ++ks) {
            bf16x8 wf[4], hf[4];
#pragma unroll
            for (int f = 0; f < 4; ++f)
                wf[f] = *(const bf16x8*)(Bt
                         + (((ks * 4 + quad) * 256) + wv * 64 + f * 16 + l15) * 8);
#pragma unroll
            for (int f = 0; f < 4; ++f)
                hf[f] = *(const bf16x8*)(At
                         + (((ks * 4 + quad) * 64) + f * 16 + l15) * 8);
#pragma unroll
            for (int fn = 0; fn < 4; ++fn)
#pragma unroll
                for (int fm = 0; fm < 4; ++fm)
                    acc[fn][fm] = __builtin_amdgcn_mfma_f32_16x16x32_bf16(
                        wf[fn], hf[fm], acc[fn][fm], 0, 0, 0);
        }

        // ================= odd tile kt+1: consume O set, load E for kt+2 =====
        __syncthreads();
#pragma unroll
        for (int L = 0; L < 8; ++L) {
            const __bf16* gp = W2T
                + (((size_t)(slab * KIT + kt + 1) * 8 + L) * 256 + wv * 64 + lane) * 8;
            __builtin_amdgcn_global_load_lds((GLOBAL_AS void*)gp,
                (LOCAL_AS void*)(Bt + (L * 256 + wv * 64) * 8), 16, 0, 0);
        }
        if (kt + 2 < KIT) {
            e_w0a = *(const float4*)(wbase + (kt + 2) * BK);
            e_w0b = *(const float4*)(wbase + (kt + 2) * BK + 4);
            e_w1a = *(const float4*)(wbase + (kt + 2) * BK + HID);
            e_w1b = *(const float4*)(wbase + (kt + 2) * BK + HID + 4);
            e_ba  = *(const float4*)(bbase + (kt + 2) * BK);
            e_bb  = *(const float4*)(bbase + (kt + 2) * BK + 4);
        }
        {
            bf16x8 hv;
            h8(hv, sv0.x, sv0.y, o_w0a, o_w0b, o_w1a, o_w1b, o_ba, o_bb);
            *(bf16x8*)(At + (octA * 64 + smpA) * 8) = hv;
            h8(hv, sv1.x, sv1.y, o_w0a, o_w0b, o_w1a, o_w1b, o_ba, o_bb);
            *(bf16x8*)(At + (octA * 64 + 32 + smpA) * 8) = hv;
        }
        __syncthreads();
#pragma unroll
        for (int ks = 0; ks < 2; ++ks) {
            bf16x8 wf[4], hf[4];
#pragma unroll
            for (int f = 0; f < 4; ++f)
                wf[f] = *(const bf16x8*)(Bt
                         + (((ks * 4 + quad) * 256) + wv * 64 + f * 16 + l15) * 8);
#pragma unroll
            for (int f = 0; f < 4; ++f)
                hf[f] = *(const bf16x8*)(At
                         + (((ks * 4 + quad) * 64) + f * 16 + l15) * 8);
#pragma unroll
            for (int fn = 0; fn < 4; ++fn)
#pragma unroll
                for (int fm = 0; fm < 4; ++fm)
                    acc[fn][fm] = __builtin_amdgcn_mfma_f32_16x16x32_bf16(
                        wf[fn], hf[fm], acc[fn][fm], 0, 0, 0);
        }
    }

    // ---- epilogue: relu(acc + b2) -> featL (K-octet-major overlay over Bt)
    __syncthreads();
#pragma unroll
    for (int fn = 0; fn < 4; ++fn) {
        const int fcb = wv * 64 + fn * 16 + quad * 4;   // featcol base
        const float4 b2v = *(const float4*)(B2 + slab * 256 + fcb);
        const int o = fcb >> 3, j = fcb & 7;
#pragma unroll
        for (int fm = 0; fm < 4; ++fm) {
            const int smp = fm * 16 + l15;
            const floatx4 v = acc[fn][fm];
            bf16x4 p;
            p[0] = (__bf16)fmaxf(v[0] + b2v.x, 0.f);
            p[1] = (__bf16)fmaxf(v[1] + b2v.y, 0.f);
            p[2] = (__bf16)fmaxf(v[2] + b2v.z, 0.f);
            p[3] = (__bf16)fmaxf(v[3] + b2v.w, 0.f);
            *(bf16x4*)(featL + (o * 64 + smp) * 8 + j) = p;
        }
    }
    __syncthreads();

    // ---- head MFMA: wave wv -> samples wv*16..+15; WHT direct (L2-hot)
    floatx4 hacc[2] = {};
#pragma unroll
    for (int ks2 = 0; ks2 < 8; ++ks2) {
        const bf16x8 fa = *(const bf16x8*)(featL
                             + ((ks2 * 4 + quad) * 64 + wv * 16 + l15) * 8);
#pragma unroll
        for (int t2 = 0; t2 < 2; ++t2) {
            const int r  = t2 * 16 + l15;
            const int og = slab * 32 + ks2 * 4 + quad;
            const bf16x8 wb = *(const bf16x8*)(WHT + (size_t)og * 256 + r * 8);
            hacc[t2] = __builtin_amdgcn_mfma_f32_16x16x32_bf16(
                fa, wb, hacc[t2], 0, 0, 0);
        }
    }

    // ---- atomic scatter: sample = quad*4+reg; emit selected skill's 4 actions
#pragma unroll
    for (int j = 0; j < 4; ++j) {
        const int smp = wv * 16 + quad * 4 + j;
        const int sk  = SK[i0 + smp];
#pragma unroll
        for (int t2 = 0; t2 < 2; ++t2) {
            const int hc = t2 * 16 + l15;
            const int d  = hc - sk * 4;
            if (d >= 0 && d < 4) {
                float v = hacc[t2][j];
                if (slab == 0) v += BH[hc];
                atomicAdd(&OUT[(i0 + smp) * 4 + d], v);
            }
        }
    }
}

extern "C" void kernel_launch(void* const* d_in, const int* in_sizes, int n_in,
                              void* d_out, int out_size, void* d_ws, size_t ws_size,
                              hipStream_t stream) {
    const float* S  = (const float*)d_in[0];
    const int*   SK = (const int*)d_in[1];
    const float* W1 = (const float*)d_in[2];
    const float* B1 = (const float*)d_in[3];
    const float* W2 = (const float*)d_in[4];
    const float* B2 = (const float*)d_in[5];
    const float* WH = (const float*)d_in[6];
    const float* BH = (const float*)d_in[7];

    char* ws = (char*)d_ws;
    __bf16* W2T = (__bf16*)ws;                          // 2 MiB
    __bf16* WHT = (__bf16*)(ws + 2 * 1024 * 1024);      // 64 KiB

    hipLaunchKernelGGL(prep_all, dim3(544), dim3(256), 0, stream,
                       W2, WH, W2T, WHT, (float*)d_out);
    // grid: 1024 sample-groups x 4 slabs; slab = blockIdx>>10 so co-resident
    // blocks share one W2T slab (L2-friendly)
    hipLaunchKernelGGL(policy_main, dim3(4096), dim3(256), 0, stream,
                       S, SK, W1, B1, W2T, B2, WHT, BH, (float*)d_out);
}